// Round 9
// baseline (94.321 us; speedup 1.0000x reference)
//
#include <hip/hip_runtime.h>

#define T_TOK 32768
#define E_EXP 256
#define K_SEL 8
#define D_DEV 8
#define SLOTS (E_EXP / D_DEV)   // 32 experts per device
#define NBLK  8192
#define TOK_PER_BLK 4           // 1 token per wave -> 4 generations of blocks

typedef float floatx4 __attribute__((ext_vector_type(4)));

// Register-resident gather kernel, multi-generation grid.
//  - 8192 blocks x 256 thr (8 blk/CU resident -> 4 dispatch generations, so
//    gather latency and store drain pipeline across generations).
//  - wave = 1 token. Lanes 0-7: meta load + parallel topk gather (one inst).
//  - expert setup (dev + stable rank) per block via ballots, as before.
//  - dense row built IN REGISTERS: 8 compile-time __shfl broadcasts of
//    (pos, score); each lane keeps float4 = positions [4L, 4L+4). No LDS
//    tile, no zero-fill, no hot-loop barrier.
//  - one wave-wide float4 store = the full 1 KB remapped row (8x128B segs).
//  - reduced_mask: per-wave ballots -> cross-wave pair OR via 16 B LDS.
__global__ __launch_bounds__(256, 8) void moe_fused_kernel(
    const float* __restrict__ topk, const int* __restrict__ mapping,
    const int* __restrict__ meta, float* __restrict__ out_remap,
    float* __restrict__ out_mask) {
  __shared__ int sdev[E_EXP];
  __shared__ int spos[E_EXP];
  __shared__ int scnt[4 * D_DEV];
  __shared__ int smask[4];

  const int tid  = threadIdx.x;
  const int w    = tid >> 6;
  const int lane = tid & 63;
  const int t    = blockIdx.x * TOK_PER_BLK + w;   // this wave's token

  // 1) meta (lanes 0-7, 32 B) then the dependent gather — issues immediately,
  //    the expert setup below hides its latency.
  int e = 0;
  float sc = 0.0f;
  if (lane < 8) {
    e  = meta[(size_t)t * K_SEL + lane];
    sc = topk[(size_t)t * E_EXP + e];
  }

  // 2) expert setup: thread tid = expert tid (argmax dev + stable rank)
  {
    const int4 m0 = ((const int4*)mapping)[tid * 2];
    const int4 m1 = ((const int4*)mapping)[tid * 2 + 1];
    int vals[8] = {m0.x, m0.y, m0.z, m0.w, m1.x, m1.y, m1.z, m1.w};
    int best = vals[0], dev = 0;
#pragma unroll
    for (int d = 1; d < 8; ++d)
      if (vals[d] > best) { best = vals[d]; dev = d; }
    sdev[tid] = dev;

    unsigned long long myball = 0ull;
#pragma unroll
    for (int d = 0; d < 8; ++d) {
      unsigned long long b = __ballot(dev == d);
      if (d == dev) myball = b;
      if (lane == d) scnt[w * 8 + d] = __popcll(b);
    }
    const unsigned long long lt = (lane == 0) ? 0ull : (~0ull >> (64 - lane));
    const int lower = __popcll(myball & lt);
    __syncthreads();
    int base = 0;
    for (int d = 0; d < dev; ++d)
      base += scnt[0 * 8 + d] + scnt[1 * 8 + d] + scnt[2 * 8 + d] +
              scnt[3 * 8 + d];
    for (int w2 = 0; w2 < w; ++w2) base += scnt[w2 * 8 + dev];
    spos[tid] = base + lower;
  }
  __syncthreads();   // publish spos/sdev for arbitrary-e reads

  // 3) remapped position + device for this lane's selection (lanes 0-7)
  int pos = 0, dv = 8;                // dv=8 sentinel for inactive lanes
  if (lane < 8) {
    pos = spos[e];
    dv  = sdev[e];
  }

  // 4) build the dense remapped row in registers: lane L owns [4L, 4L+4)
  float4 row = {0.f, 0.f, 0.f, 0.f};
#pragma unroll
  for (int g = 0; g < 8; ++g) {
    const int   pg = __shfl(pos, g, 64);   // compile-time lane -> v_readlane
    const float sg = __shfl(sc, g, 64);
    const bool mine = (pg >> 2) == lane;
    const int c = pg & 3;                  // wave-uniform
    row.x = (mine && c == 0) ? sg : row.x;
    row.y = (mine && c == 1) ? sg : row.y;
    row.z = (mine && c == 2) ? sg : row.z;
    row.w = (mine && c == 3) ? sg : row.w;
  }

  // 5) one wave-wide store: full 1 KB remapped row (8 x 128 B segments)
  float* dst = out_remap + (size_t)(lane >> 3) * T_TOK * SLOTS +
               (size_t)t * SLOTS + (lane & 7) * 4;
  __builtin_nontemporal_store(*(floatx4*)&row, (floatx4*)dst);

  // 6) reduced_mask: per-wave device mask, OR over the (even,odd) wave pair
  unsigned dmask = 0;
#pragma unroll
  for (int d = 0; d < D_DEV; ++d) {
    const unsigned long long b = __ballot(dv == d);
    dmask |= (b ? 1u : 0u) << d;
  }
  if (lane == 0) smask[w] = (int)dmask;
  __syncthreads();
  if ((w & 1) == 0 && lane < 8) {
    const unsigned comb = (unsigned)smask[w] | (unsigned)smask[w + 1];
    out_mask[(size_t)(t >> 1) * D_DEV + lane] =
        ((comb >> lane) & 1u) ? 1.0f : 0.0f;
  }
}

extern "C" void kernel_launch(void* const* d_in, const int* in_sizes, int n_in,
                              void* d_out, int out_size, void* d_ws, size_t ws_size,
                              hipStream_t stream) {
  const float* topk    = (const float*)d_in[0];
  const int*   mapping = (const int*)d_in[1];
  const int*   meta    = (const int*)d_in[2];

  float* out_remap = (float*)d_out;
  float* out_mask  = out_remap + (size_t)D_DEV * T_TOK * SLOTS;  // 8,388,608

  moe_fused_kernel<<<NBLK, 256, 0, stream>>>(topk, mapping, meta, out_remap,
                                             out_mask);
}

// Round 10
// 86.909 us; speedup vs baseline: 1.0853x; 1.0853x over previous
//
#include <hip/hip_runtime.h>

#define T_TOK 32768
#define E_EXP 256
#define K_SEL 8
#define D_DEV 8
#define SLOTS (E_EXP / D_DEV)   // 32 experts per device
#define NBLK  512
#define BTHR  1024
#define TOK_PER_BLK 64
#define TOK_PER_IT  16
#define NIT   4
#define ROWP  264               // padded tile row (floats)

typedef float floatx4 __attribute__((ext_vector_type(4)));

// Persistent pipelined gather kernel.
//  512 blocks x 1024 thr -> 2 blocks/CU x 16 waves = 32 waves/CU (HW max).
//  Block owns 64 tokens = 4 iterations x 16 tokens, software-pipelined:
//  the gather for iteration i+1 is issued BEFORE iteration i's write-out,
//  so scattered reads overlap the streaming stores continuously (the copy-
//  ubench structure), instead of one read burst then one store drain.
//  - threads 0-127: (token tl=tid>>3, k=tid&7) gather lanes; meta for all 4
//    iterations loaded up front (4 coalesced 512 B loads per wave pair).
//  - per-iteration: zero 16x264 tile (<=2-way banks), barrier, scatter by
//    remapped position (gating by construction) + mask ballots, barrier,
//    write-out 1024 x float4 (1 KB contiguous per wave-inst), barrier.
//  - expert setup (argmax dev + stable rank) once per block via ballots in
//    waves 0-3, amortized over 64 tokens.
__global__ __launch_bounds__(BTHR, 8) void moe_fused_kernel(
    const float* __restrict__ topk, const int* __restrict__ mapping,
    const int* __restrict__ meta, float* __restrict__ out_remap,
    float* __restrict__ out_mask) {
  __shared__ float tile[TOK_PER_IT * ROWP];   // 16.9 KB
  __shared__ int sdev[E_EXP];
  __shared__ int spos[E_EXP];
  __shared__ int scnt[4 * D_DEV];

  const int tid  = threadIdx.x;
  const int w    = tid >> 6;
  const int lane = tid & 63;
  const int tbase = blockIdx.x * TOK_PER_BLK;
  const int tl = tid >> 3;              // gather token within iteration (0-15)

  // 1) meta for all 4 iterations (threads 0-127), then the first gather —
  //    issued before setup so its latency hides under the ballots.
  int e[NIT] = {0, 0, 0, 0};
  float sc_cur = 0.0f;
  if (tid < 128) {
#pragma unroll
    for (int i = 0; i < NIT; ++i)
      e[i] = meta[(size_t)(tbase + i * TOK_PER_IT) * K_SEL + tid];
    sc_cur = topk[(size_t)(tbase + tl) * E_EXP + e[0]];
  }

  // 2) expert setup: waves 0-3, thread tid = expert tid
  int dev = 0, lower = 0;
  if (tid < 256) {
    const int4 m0 = ((const int4*)mapping)[tid * 2];
    const int4 m1 = ((const int4*)mapping)[tid * 2 + 1];
    int vals[8] = {m0.x, m0.y, m0.z, m0.w, m1.x, m1.y, m1.z, m1.w};
    int best = vals[0];
#pragma unroll
    for (int d = 1; d < 8; ++d)
      if (vals[d] > best) { best = vals[d]; dev = d; }
    sdev[tid] = dev;

    unsigned long long myball = 0ull;
#pragma unroll
    for (int d = 0; d < 8; ++d) {
      unsigned long long b = __ballot(dev == d);
      if (d == dev) myball = b;
      if (lane == d) scnt[w * 8 + d] = __popcll(b);
    }
    const unsigned long long lt = (lane == 0) ? 0ull : (~0ull >> (64 - lane));
    lower = __popcll(myball & lt);
  }
  __syncthreads();
  if (tid < 256) {
    int base = 0;
    for (int d = 0; d < dev; ++d)
      base += scnt[0 * 8 + d] + scnt[1 * 8 + d] + scnt[2 * 8 + d] +
              scnt[3 * 8 + d];
    for (int w2 = 0; w2 < w; ++w2) base += scnt[w2 * 8 + dev];
    spos[tid] = base + lower;
  }
  __syncthreads();   // publish spos/sdev

  const floatx4 z4 = {0.f, 0.f, 0.f, 0.f};

  // 3) pipelined iterations
#pragma unroll
  for (int i = 0; i < NIT; ++i) {
    // prefetch next iteration's gather (independent of everything below;
    // flies while this iteration scatters and stores)
    float sc_next = 0.0f;
    if (i + 1 < NIT && tid < 128)
      sc_next =
          topk[(size_t)(tbase + (i + 1) * TOK_PER_IT + tl) * E_EXP + e[i + 1]];

    // zero-fill the tile (same footprint as write-out; pad untouched)
    {
      const int a = ((tid >> 3) & 15) * ROWP + (tid >> 7) * SLOTS +
                    (tid & 7) * 4;
      *(floatx4*)&tile[a] = z4;
    }
    __syncthreads();

    // scatter + reduced_mask (threads 0-127 = waves 0-1, fully active)
    if (tid < 128) {
      const int pos = spos[e[i]];
      const int dv  = sdev[e[i]];
      tile[tl * ROWP + pos] = sc_cur;   // gating by construction

      unsigned long long bsel = 0ull;
#pragma unroll
      for (int d = 0; d < D_DEV; ++d) {
        unsigned long long b = __ballot(dv == d);
        if ((lane & 7) == d) bsel = b;
      }
      if (lane < 32) {
        const float fm =
            ((bsel >> (16 * (lane >> 3))) & 0xFFFFull) ? 1.0f : 0.0f;
        const int rowi =
            ((tbase + i * TOK_PER_IT) >> 1) + (w << 2) + (lane >> 3);
        out_mask[(size_t)rowi * D_DEV + (lane & 7)] = fm;
      }
    }
    __syncthreads();

    // write-out: 1024 threads x float4 = the full 16 KB tile; each wave-inst
    // stores 1 KB contiguous (8 tokens x 128 B within one device chunk)
    {
      const int t16    = (tid >> 3) & 15;
      const int dchunk = tid >> 7;
      const int j      = (tid & 7) * 4;
      const floatx4 v = *(const floatx4*)&tile[t16 * ROWP + dchunk * SLOTS + j];
      *(floatx4*)(out_remap + (size_t)dchunk * T_TOK * SLOTS +
                  (size_t)(tbase + i * TOK_PER_IT + t16) * SLOTS + j) = v;
    }
    sc_cur = sc_next;
    __syncthreads();   // tile ds_reads complete before next zero-fill
  }
}

extern "C" void kernel_launch(void* const* d_in, const int* in_sizes, int n_in,
                              void* d_out, int out_size, void* d_ws, size_t ws_size,
                              hipStream_t stream) {
  const float* topk    = (const float*)d_in[0];
  const int*   mapping = (const int*)d_in[1];
  const int*   meta    = (const int*)d_in[2];

  float* out_remap = (float*)d_out;
  float* out_mask  = out_remap + (size_t)D_DEV * T_TOK * SLOTS;  // 8,388,608

  moe_fused_kernel<<<NBLK, BTHR, 0, stream>>>(topk, mapping, meta, out_remap,
                                              out_mask);
}